// Round 8
// baseline (70.288 us; speedup 1.0000x reference)
//
#include <hip/hip_runtime.h>
#include <hip/hip_bf16.h>

// HMM forward via paired-step segmented matrix products (R8).
//
//   S_{t+1} S_t = diag(e_{t+1}) * G2[x_t],   G2[m] = A * diag(e_m) * A
//
// R8 = R7 (verified) + one structural change in hmm_seg:
//   NO LDS. The 33KB G2 table is L2-resident (read by all 256 CUs); gf/ev
//   fragments are loaded straight from global (gf: coalesced b64/lane;
//   ev: broadcast f32x4 -> also kills the 4 bf16-unpack shifts per pair).
//   This removes the 33KB/block staging preamble + syncthreads and the
//   4-block/CU LDS residency cap that held occupancy at ~25%. Blocks are
//   now 256 threads = 4 waves = 4 same-batch segments, launch_bounds(256,8)
//   -> up to 32 waves/CU, 4096 blocks backfill smoothly.
// Setup and comb verbatim R7.

#define NS    16
#define MOBS  64
#define SSH   5            // log2(nseg); nseg=32 -> L<=128 -> npair<=64
#define NSEG  32

typedef float f32x4 __attribute__((ext_vector_type(4)));
typedef short s16x4 __attribute__((ext_vector_type(4)));

static __device__ __forceinline__ int imin(int a, int b){ return a < b ? a : b; }

static __device__ __forceinline__ unsigned short f2bf(float f){
  return __bfloat16_as_ushort(__float2bfloat16(f));   // RNE (setup only)
}
static __device__ __forceinline__ float b2f(unsigned short u){
  unsigned bits = ((unsigned)u) << 16;
  return __builtin_bit_cast(float, bits);
}

// packed f32x2 -> bf16x2 (hardware RNE; no builtin on gfx950 -> inline asm)
static __device__ __forceinline__ s16x4 pack_bf16x4(f32x4 C){
  unsigned r0, r1;
  asm("v_cvt_pk_bf16_f32 %0, %1, %2" : "=v"(r0) : "v"(C.x), "v"(C.y));
  asm("v_cvt_pk_bf16_f32 %0, %1, %2" : "=v"(r1) : "v"(C.z), "v"(C.w));
  uint2 pu; pu.x = r0; pu.y = r1;
  return __builtin_bit_cast(s16x4, pu);
}

#if __has_builtin(__builtin_amdgcn_mfma_f32_16x16x16bf16_1k)
static __device__ __forceinline__ f32x4 mfma16(s16x4 a, s16x4 b, f32x4 c){
  return __builtin_amdgcn_mfma_f32_16x16x16bf16_1k(a, b, c, 0, 0, 0);
}
#else
static __device__ __forceinline__ f32x4 mfma16(s16x4 a, s16x4 b, f32x4 c){
  f32x4 d;
  asm volatile("v_mfma_f32_16x16x16_bf16 %0, %1, %2, %3"
               : "=&v"(d) : "v"(a), "v"(b), "v"(c));
  return d;
}
#endif

// ---------------- ws byte layout ----------------
//     0 : ET  f32 [64][16], ET[m][i] = P(obs m | state i)   (4096 B)
//  4096 : pi  f32 [16]                                      (64 B)
//  8192 : g2  ushort:
//            [0,16384)      G2 slots 0..63 (MFMA A-frag order)
//            [16384,16640)  slot 64 = plain A frag (odd tails)
//            [16640,17664)  ET bf16 [64][16]   (kept; unused by R8 seg)
// 49152 : Q   ushort [B][NSEG][256]  (row-major [row][col])
//  then : CE  int    [B][NSEG][16]
// -------------------------------------------------

// One kernel: all softmax normalizations + G2 table build (verbatim R7).
__global__ void hmm_setup(const float* __restrict__ tl, const float* __restrict__ el,
                          const float* __restrict__ pl, float* __restrict__ ws,
                          unsigned short* __restrict__ g2)
{
  int m = blockIdx.x, t = threadIdx.x;   // 65 blocks x 256 threads
  __shared__ float Al[256];
  __shared__ float ev[16];
  if (t < 16){
    // A column t (softmax over rows, axis=0)
    float mx = -3.0e38f;
    for (int i = 0; i < 16; ++i) mx = fmaxf(mx, tl[i*NS + t]);
    float sm = 0.f;
    for (int i = 0; i < 16; ++i) sm += expf(tl[i*NS + t] - mx);
    float inv = 1.f / sm;
    for (int i = 0; i < 16; ++i) Al[i*16 + t] = expf(tl[i*NS + t] - mx) * inv;
  } else if (t < 32){
    int i = t - 16;
    if (m < 64){
      // e_m[i] = softmax_m(E row i) at column m ; also persist ET row m
      float mx = -3.0e38f;
      for (int mm = 0; mm < MOBS; ++mm) mx = fmaxf(mx, el[i*MOBS + mm]);
      float sm = 0.f;
      for (int mm = 0; mm < MOBS; ++mm) sm += expf(el[i*MOBS + mm] - mx);
      float v = expf(el[i*MOBS + m] - mx) / sm;
      ev[i] = v;
      ws[m*16 + i] = v;
      g2[16640 + m*16 + i] = f2bf(v);      // bf16 ET (unused by R8 seg; cheap)
    } else ev[i] = 1.f;
  } else if (t < 48 && m == 64){
    int i = t - 32;
    float mx = -3.0e38f;
    for (int k = 0; k < 16; ++k) mx = fmaxf(mx, pl[k]);
    float sm = 0.f;
    for (int k = 0; k < 16; ++k) sm += expf(pl[k] - mx);
    ws[1024 + i] = expf(pl[i] - mx) / sm;
  }
  __syncthreads();
  int l = t >> 2, e = t & 3;
  int i = l & 15, col = ((l >> 4) << 2) + e;    // A-frag: lane l = row l&15, cols 4*(l>>4)+e
  float acc;
  if (m == 64){
    acc = Al[i*16 + col];
  } else {
    acc = 0.f;
    #pragma unroll
    for (int k = 0; k < 16; ++k) acc += Al[i*16 + k] * ev[k] * Al[k*16 + col];
  }
  g2[(m*64 + l)*4 + e] = f2bf(acc);
}

// 4 pair-steps; prefetches quad+1's fragments from GLOBAL (L2-resident table)
// via readlane(xp, p0+4+p). MASK: pairs with p0+p >= npair computed
// (valid-but-garbage indices) but not committed. REN: renorm at p==3.
template<bool MASK, bool REN>
static __device__ __forceinline__ void run_quad(
    int p0, int npair,
    const unsigned short* __restrict__ g2, const float* __restrict__ et,
    int lane4, int g4, int xp, s16x4& P, int& ce,
    s16x4 (&gf)[4], f32x4 (&ev)[4], s16x4 (&gfn)[4], f32x4 (&evn)[4])
{
  const f32x4 Z = {0.f, 0.f, 0.f, 0.f};
  #pragma unroll
  for (int p = 0; p < 4; ++p){
    int v = __builtin_amdgcn_readlane(xp, (p0 + 4 + p) & 63);
    gfn[p] = *(const s16x4*)&g2[(v & 63)*256 + lane4];
    evn[p] = *(const f32x4*)&et[((v >> 8) & 63)*16 + g4];

    f32x4 C = mfma16(gf[p], P, Z);               // C = G2[x_t] * P
    C.x *= ev[p].x; C.y *= ev[p].y;              // rows scaled by e_{t+1}
    C.z *= ev[p].z; C.w *= ev[p].w;

    bool commit = (!MASK) || (p0 + p < npair);
    if (REN && p == 3){
      float mm = fmaxf(fmaxf(C.x, C.y), fmaxf(C.z, C.w));
      mm = fmaxf(mm, __shfl_xor(mm, 16));
      mm = fmaxf(mm, __shfl_xor(mm, 32));
      int kk; (void)frexpf(mm, &kk);
      if (commit){
        C.x = ldexpf(C.x, -kk); C.y = ldexpf(C.y, -kk);
        C.z = ldexpf(C.z, -kk); C.w = ldexpf(C.w, -kk);
        ce += kk;
      }
    }
    if (commit){
      P = pack_bf16x4(C);                        // C layout == B layout (R0-verified)
    }
  }
}

__global__ __launch_bounds__(256, 8) void hmm_seg(
    const int* __restrict__ x, const int* __restrict__ Tl,
    const float* __restrict__ ws, const unsigned short* __restrict__ g2,
    unsigned short* __restrict__ Q, int* __restrict__ CE,
    int TMAX, int XN)
{
  int tid  = threadIdx.x;
  int lane = tid & 63;
  int wid  = __builtin_amdgcn_readfirstlane(tid >> 6);
  int g = lane >> 4, j = lane & 15;
  int lane4 = lane * 4, g4 = g * 4;

  int gseg = blockIdx.x * 4 + wid;          // 4 waves = 4 consecutive segments
  int b = gseg >> SSH, s = gseg & (NSEG - 1);

  int steps = __builtin_amdgcn_readfirstlane(Tl[b]) - 1;
  int L  = (steps + NSEG - 1) >> SSH;       // even split; L <= 128 -> npair <= 64
  int lo = s * L;
  int n  = imin(steps - lo, L);

  unsigned short* Qout = Q + (size_t)gseg * 256;
  int* ceout = CE + gseg * NS;

  if (n <= 0){                              // empty segment -> identity, no LDS: cheap exit
    if (g == 0) ceout[j] = 0;
    #pragma unroll
    for (int e = 0; e < 4; ++e){
      int k = 4*g + e;
      Qout[k*16 + j] = (k == j) ? (unsigned short)0x3F80 : (unsigned short)0;
    }
    return;
  }

  int npair = n >> 1, odd = n & 1;
  int xbase = b*TMAX + 1 + lo;

  // lane i holds packed observation pair (x[2i], x[2i+1]) for the whole segment
  int i0 = xbase + 2*lane;
  int xa = x[imin(i0,     XN - 1)] & 63;
  int xb = x[imin(i0 + 1, XN - 1)] & 63;
  int xp = xa | (xb << 8);

  const float* et = ws;                     // ET f32 [64][16]

  s16x4 P;                                  // identity in B-frag layout
  P.x = (4*g+0 == j) ? (short)0x3F80 : (short)0;
  P.y = (4*g+1 == j) ? (short)0x3F80 : (short)0;
  P.z = (4*g+2 == j) ? (short)0x3F80 : (short)0;
  P.w = (4*g+3 == j) ? (short)0x3F80 : (short)0;

  s16x4 gfA[4], gfB[4];
  f32x4 evA[4], evB[4];
  #pragma unroll
  for (int p = 0; p < 4; ++p){
    int v = __builtin_amdgcn_readlane(xp, p);
    gfA[p] = *(const s16x4*)&g2[(v & 63)*256 + lane4];
    evA[p] = *(const f32x4*)&et[((v >> 8) & 63)*16 + g4];
  }

  int ce = 0, p0 = 0;
  while (p0 + 8 <= npair){
    run_quad<false,false>(p0,   npair, g2, et, lane4, g4, xp, P, ce, gfA, evA, gfB, evB);
    run_quad<false,true >(p0+4, npair, g2, et, lane4, g4, xp, P, ce, gfB, evB, gfA, evA);
    p0 += 8;
  }
  if (p0 < npair){
    run_quad<true,true>(p0, npair, g2, et, lane4, g4, xp, P, ce, gfA, evA, gfB, evB);
    if (p0 + 4 < npair)
      run_quad<true,true>(p0+4, npair, g2, et, lane4, g4, xp, P, ce, gfB, evB, gfA, evA);
  }

  if (odd){                                 // trailing single step: diag(e)*A
    int v = __builtin_amdgcn_readlane(xp, (n - 1) >> 1);
    int xm = v & 63;                        // n-1 even -> first obs of that pair
    s16x4 af = *(const s16x4*)&g2[16384 + lane4];   // slot 64 = A frag
    f32x4 evo = *(const f32x4*)&et[xm*16 + g4];
    const f32x4 Z = {0.f,0.f,0.f,0.f};
    f32x4 C = mfma16(af, P, Z);
    C.x *= evo.x; C.y *= evo.y; C.z *= evo.z; C.w *= evo.w;
    P = pack_bf16x4(C);
  }

  if (g == 0) ceout[j] = ce;
  unsigned short pb[4] = {(unsigned short)P.x, (unsigned short)P.y,
                          (unsigned short)P.z, (unsigned short)P.w};
  #pragma unroll
  for (int e = 0; e < 4; ++e) Qout[(4*g + e)*16 + j] = pb[e];
}

// Combine (verbatim R7): 4 batches/block, one wave per batch; reference
// exponent = readlane(CE[0]); u rescaled once/segment by lane-0 frexp.
__global__ __launch_bounds__(256) void hmm_comb(
    const int* __restrict__ x, const float* __restrict__ ws,
    const unsigned short* __restrict__ Q, const int* __restrict__ CE,
    float* __restrict__ out, int TMAX)
{
  int lane = threadIdx.x & 63;
  int w    = threadIdx.x >> 6;
  int b    = blockIdx.x * 4 + w;
  int k = lane & 15, r = lane >> 4;

  int x0 = x[b*TMAX];
  float u = ws[1024 + k] * ws[x0*16 + k];   // alpha0 = pi * E[:,x0]
  int ce_tot = 0;

  const unsigned short* qb = Q  + (size_t)b * NSEG * 256;
  const int*            cb = CE + b * NSEG * 16;

  // prefetch segment 0
  s16x4 qq = *(const s16x4*)&qb[k*16 + 4*r];       // row k, cols 4r..4r+3
  int4  cv = *(const int4*)&cb[4*r];               // ce[4r..4r+3]

  for (int s = 0; s < NSEG; ++s){
    s16x4 qn; int4 cn;
    if (s + 1 < NSEG){                             // prefetch next segment
      qn = *(const s16x4*)&qb[(s+1)*256 + k*16 + 4*r];
      cn = *(const int4*)&cb[(s+1)*16 + 4*r];
    }
    int c0 = __builtin_amdgcn_readlane(cv.x, 0);   // ce[0] (lane 0: k=0,r=0)
    float m0 = ldexpf(b2f((unsigned short)qq.x), cv.x - c0);
    float m1 = ldexpf(b2f((unsigned short)qq.y), cv.y - c0);
    float m2 = ldexpf(b2f((unsigned short)qq.z), cv.z - c0);
    float m3 = ldexpf(b2f((unsigned short)qq.w), cv.w - c0);

    float u0 = __shfl(u, 4*r + 0);
    float u1 = __shfl(u, 4*r + 1);
    float u2 = __shfl(u, 4*r + 2);
    float u3 = __shfl(u, 4*r + 3);
    float acc = m0*u0 + m1*u1 + m2*u2 + m3*u3;
    acc += __shfl_xor(acc, 16);
    acc += __shfl_xor(acc, 32);                    // full u_new[k] on all r-copies

    int ek; (void)frexpf(acc, &ek);                // exponent of own component
    int k0 = __builtin_amdgcn_readlane(ek, 0);     // rescale by component 0
    u = ldexpf(acc, -k0);
    ce_tot += c0 + k0;

    qq = qn; cv = cn;
  }

  float sm = u;
  sm += __shfl_xor(sm, 1);
  sm += __shfl_xor(sm, 2);
  sm += __shfl_xor(sm, 4);
  sm += __shfl_xor(sm, 8);
  if (lane == 0) out[b] = ldexpf(sm, ce_tot);
}

extern "C" void kernel_launch(void* const* d_in, const int* in_sizes, int n_in,
                              void* d_out, int out_size, void* d_ws, size_t ws_size,
                              hipStream_t stream)
{
  (void)n_in; (void)out_size; (void)ws_size;
  const int*   x  = (const int*)  d_in[0];
  const int*   T  = (const int*)  d_in[1];
  const float* tl = (const float*)d_in[2];
  const float* el = (const float*)d_in[3];
  const float* pl = (const float*)d_in[4];
  int B    = in_sizes[1];
  int TMAX = in_sizes[0] / B;
  int XN   = B * TMAX;

  float* ws = (float*)d_ws;
  unsigned short* g2 = (unsigned short*)((char*)d_ws + 8192);
  unsigned short* Q  = (unsigned short*)((char*)d_ws + 49152);
  int* CE = (int*)((char*)d_ws + 49152 + (size_t)B * NSEG * 512);
  float* out = (float*)d_out;

  hipLaunchKernelGGL(hmm_setup, dim3(65),          dim3(256), 0, stream, tl, el, pl, ws, g2);
  hipLaunchKernelGGL(hmm_seg,   dim3(B*NSEG/4),    dim3(256), 0, stream, x, T, ws, g2, Q, CE, TMAX, XN);
  hipLaunchKernelGGL(hmm_comb,  dim3(B/4),         dim3(256), 0, stream, x, ws, Q, CE, out, TMAX);
}

// Round 10
// 50.528 us; speedup vs baseline: 1.3911x; 1.3911x over previous
//
#include <hip/hip_runtime.h>
#include <hip/hip_bf16.h>

// HMM forward via paired-step segmented matrix products (R10).
//
//   S_{t+1} S_t = diag(e_{t+1}) * G2[x_t],   G2[m] = A * diag(e_m) * A
//
// R10 = R7 (verified, best @50.7us) + ONE line per pair-step:
//   asm volatile("" ::: "memory") at the end of each pair's body.
// Theory: VGPR_Count=32 across all rounds proves the compiler sinks the
// prefetch ds_reads to their uses (prefetch arrays alone need >48 VGPRs),
// putting ~120-260cy of LDS latency in the MFMA dependent chain. The IR-level
// memory clobber stops loads from sinking across pair boundaries (>=4 pairs
// = ~180cy of compute ahead of use) WITHOUT touching the post-RA scheduler
// (sched_barrier(0) miscompiled -> R9 NaN; lesson recorded).

#define NS    16
#define MOBS  64
#define SSH   5            // log2(nseg); nseg=32 -> L<=128 -> npair<=64
#define NSEG  32

typedef float f32x4 __attribute__((ext_vector_type(4)));
typedef short s16x4 __attribute__((ext_vector_type(4)));

static __device__ __forceinline__ int imin(int a, int b){ return a < b ? a : b; }

static __device__ __forceinline__ unsigned short f2bf(float f){
  return __bfloat16_as_ushort(__float2bfloat16(f));   // RNE (setup only)
}
static __device__ __forceinline__ float b2f(unsigned short u){
  unsigned bits = ((unsigned)u) << 16;
  return __builtin_bit_cast(float, bits);
}

// packed f32x2 -> bf16x2 (hardware RNE; no builtin on gfx950 -> inline asm)
static __device__ __forceinline__ s16x4 pack_bf16x4(f32x4 C){
  unsigned r0, r1;
  asm("v_cvt_pk_bf16_f32 %0, %1, %2" : "=v"(r0) : "v"(C.x), "v"(C.y));
  asm("v_cvt_pk_bf16_f32 %0, %1, %2" : "=v"(r1) : "v"(C.z), "v"(C.w));
  uint2 pu; pu.x = r0; pu.y = r1;
  return __builtin_bit_cast(s16x4, pu);
}

#if __has_builtin(__builtin_amdgcn_mfma_f32_16x16x16bf16_1k)
static __device__ __forceinline__ f32x4 mfma16(s16x4 a, s16x4 b, f32x4 c){
  return __builtin_amdgcn_mfma_f32_16x16x16bf16_1k(a, b, c, 0, 0, 0);
}
#else
static __device__ __forceinline__ f32x4 mfma16(s16x4 a, s16x4 b, f32x4 c){
  f32x4 d;
  asm volatile("v_mfma_f32_16x16x16_bf16 %0, %1, %2, %3"
               : "=&v"(d) : "v"(a), "v"(b), "v"(c));
  return d;
}
#endif

// ---------------- ws byte layout ----------------
//     0 : ET  f32 [64][16], ET[m][i] = P(obs m | state i)   (4096 B)
//  4096 : pi  f32 [16]                                      (64 B)
//  8192 : g2  ushort:
//            [0,16384)      G2 slots 0..63 (MFMA A-frag order)
//            [16384,16640)  slot 64 = plain A frag (odd tails)
//            [16640,17664)  ET bf16 [64][16]
// 49152 : Q   ushort [B][NSEG][256]  (row-major [row][col])
//  then : CE  int    [B][NSEG][16]
// -------------------------------------------------

// One kernel: all softmax normalizations + G2 table build (verbatim R7).
__global__ void hmm_setup(const float* __restrict__ tl, const float* __restrict__ el,
                          const float* __restrict__ pl, float* __restrict__ ws,
                          unsigned short* __restrict__ g2)
{
  int m = blockIdx.x, t = threadIdx.x;   // 65 blocks x 256 threads
  __shared__ float Al[256];
  __shared__ float ev[16];
  if (t < 16){
    // A column t (softmax over rows, axis=0)
    float mx = -3.0e38f;
    for (int i = 0; i < 16; ++i) mx = fmaxf(mx, tl[i*NS + t]);
    float sm = 0.f;
    for (int i = 0; i < 16; ++i) sm += expf(tl[i*NS + t] - mx);
    float inv = 1.f / sm;
    for (int i = 0; i < 16; ++i) Al[i*16 + t] = expf(tl[i*NS + t] - mx) * inv;
  } else if (t < 32){
    int i = t - 16;
    if (m < 64){
      // e_m[i] = softmax_m(E row i) at column m ; also persist ET row m
      float mx = -3.0e38f;
      for (int mm = 0; mm < MOBS; ++mm) mx = fmaxf(mx, el[i*MOBS + mm]);
      float sm = 0.f;
      for (int mm = 0; mm < MOBS; ++mm) sm += expf(el[i*MOBS + mm] - mx);
      float v = expf(el[i*MOBS + m] - mx) / sm;
      ev[i] = v;
      ws[m*16 + i] = v;
      g2[16640 + m*16 + i] = f2bf(v);      // bf16 ET for seg LDS
    } else ev[i] = 1.f;
  } else if (t < 48 && m == 64){
    int i = t - 32;
    float mx = -3.0e38f;
    for (int k = 0; k < 16; ++k) mx = fmaxf(mx, pl[k]);
    float sm = 0.f;
    for (int k = 0; k < 16; ++k) sm += expf(pl[k] - mx);
    ws[1024 + i] = expf(pl[i] - mx) / sm;
  }
  __syncthreads();
  int l = t >> 2, e = t & 3;
  int i = l & 15, col = ((l >> 4) << 2) + e;    // A-frag: lane l = row l&15, cols 4*(l>>4)+e
  float acc;
  if (m == 64){
    acc = Al[i*16 + col];
  } else {
    acc = 0.f;
    #pragma unroll
    for (int k = 0; k < 16; ++k) acc += Al[i*16 + k] * ev[k] * Al[k*16 + col];
  }
  g2[(m*64 + l)*4 + e] = f2bf(acc);
}

// 4 pair-steps; prefetches quad+1's LDS fragments via readlane(xp, p0+4+p).
// A memory clobber ends each pair's region: prefetch loads cannot sink
// across it -> issued >=4 pairs ahead of use, values kept live in VGPRs.
// MASK: pairs with p0+p >= npair computed (garbage) but not committed.
// REN: renorm at p==3 (applied every other quad -> every 8 pairs).
template<bool MASK, bool REN>
static __device__ __forceinline__ void run_quad(
    int p0, int npair,
    const unsigned short* g2l, const unsigned short* etl,
    int lane4, int g4, int xp, s16x4& P, int& ce,
    s16x4 (&gf)[4], s16x4 (&ev)[4], s16x4 (&gfn)[4], s16x4 (&evn)[4])
{
  const f32x4 Z = {0.f, 0.f, 0.f, 0.f};
  #pragma unroll
  for (int p = 0; p < 4; ++p){
    int v = __builtin_amdgcn_readlane(xp, (p0 + 4 + p) & 63);
    gfn[p] = *(const s16x4*)&g2l[(v & 63)*256 + lane4];
    evn[p] = *(const s16x4*)&etl[((v >> 8) & 63)*16 + g4];

    f32x4 C = mfma16(gf[p], P, Z);               // C = G2[x_t] * P
    C.x *= b2f((unsigned short)ev[p].x);         // rows scaled by e_{t+1}
    C.y *= b2f((unsigned short)ev[p].y);
    C.z *= b2f((unsigned short)ev[p].z);
    C.w *= b2f((unsigned short)ev[p].w);

    bool commit = (!MASK) || (p0 + p < npair);
    if (REN && p == 3){
      float mm = fmaxf(fmaxf(C.x, C.y), fmaxf(C.z, C.w));
      mm = fmaxf(mm, __shfl_xor(mm, 16));
      mm = fmaxf(mm, __shfl_xor(mm, 32));
      int kk; (void)frexpf(mm, &kk);
      if (commit){
        C.x = ldexpf(C.x, -kk); C.y = ldexpf(C.y, -kk);
        C.z = ldexpf(C.z, -kk); C.w = ldexpf(C.w, -kk);
        ce += kk;
      }
    }
    if (commit){
      P = pack_bf16x4(C);                        // C layout == B layout (R0-verified)
    }
    asm volatile("" ::: "memory");               // pair-region boundary: no load sinking
  }
}

__global__ __launch_bounds__(512, 1) void hmm_seg(
    const int* __restrict__ x, const int* __restrict__ Tl,
    const unsigned short* __restrict__ g2,
    unsigned short* __restrict__ Q, int* __restrict__ CE,
    int TMAX, int XN)
{
  int tid  = threadIdx.x;
  int lane = tid & 63;
  int wid  = __builtin_amdgcn_readfirstlane(tid >> 6);
  int g = lane >> 4, j = lane & 15;
  int lane4 = lane * 4, g4 = g * 4;

  int gseg = blockIdx.x * 8 + wid;
  int b = gseg >> SSH, s = gseg & (NSEG - 1);

  int steps = __builtin_amdgcn_readfirstlane(Tl[b]) - 1;
  int L  = (steps + NSEG - 1) >> SSH;       // even split; L <= 128 -> npair <= 64
  int lo = s * L;
  int n  = imin(steps - lo, L);

  unsigned short* Qout = Q + (size_t)gseg * 256;
  int* ceout = CE + gseg * NS;

  // Block-level fast path: all 8 segments of this block empty -> identities,
  // exit BEFORE LDS staging (block-uniform condition).
  int s_lo = (blockIdx.x & 3) * 8;
  if (s_lo * L >= steps){
    if (g == 0) ceout[j] = 0;
    #pragma unroll
    for (int e = 0; e < 4; ++e){
      int k = 4*g + e;
      Qout[k*16 + j] = (k == j) ? (unsigned short)0x3F80 : (unsigned short)0;
    }
    return;
  }

  __shared__ unsigned short g2l[64*256];   // 32768 B
  __shared__ unsigned short etl[1024];     //  2048 B -> 34816 total
  {
    const uint4* s1 = (const uint4*)g2;                 // 2048 x uint4 (G2)
    const uint4* s2 = (const uint4*)(g2 + 16640);       //  128 x uint4 (ET bf16)
    uint4* d1 = (uint4*)g2l;
    uint4* d2 = (uint4*)etl;
    for (int i = tid; i < 2048; i += 512) d1[i] = s1[i];
    if (tid < 128) d2[tid] = s2[tid];
  }
  __syncthreads();

  if (n <= 0){                              // this wave's segment empty -> identity
    if (g == 0) ceout[j] = 0;
    #pragma unroll
    for (int e = 0; e < 4; ++e){
      int k = 4*g + e;
      Qout[k*16 + j] = (k == j) ? (unsigned short)0x3F80 : (unsigned short)0;
    }
    return;
  }

  int npair = n >> 1, odd = n & 1;
  int xbase = b*TMAX + 1 + lo;

  // lane i holds packed observation pair (x[2i], x[2i+1]) for the whole segment
  int i0 = xbase + 2*lane;
  int xa = x[imin(i0,     XN - 1)] & 63;
  int xb = x[imin(i0 + 1, XN - 1)] & 63;
  int xp = xa | (xb << 8);

  s16x4 P;                                  // identity in B-frag layout
  P.x = (4*g+0 == j) ? (short)0x3F80 : (short)0;
  P.y = (4*g+1 == j) ? (short)0x3F80 : (short)0;
  P.z = (4*g+2 == j) ? (short)0x3F80 : (short)0;
  P.w = (4*g+3 == j) ? (short)0x3F80 : (short)0;

  s16x4 gfA[4], gfB[4], evA[4], evB[4];
  #pragma unroll
  for (int p = 0; p < 4; ++p){
    int v = __builtin_amdgcn_readlane(xp, p);
    gfA[p] = *(const s16x4*)&g2l[(v & 63)*256 + lane4];
    evA[p] = *(const s16x4*)&etl[((v >> 8) & 63)*16 + g4];
  }

  int ce = 0, p0 = 0;
  while (p0 + 8 <= npair){
    run_quad<false,false>(p0,   npair, g2l, etl, lane4, g4, xp, P, ce, gfA, evA, gfB, evB);
    run_quad<false,true >(p0+4, npair, g2l, etl, lane4, g4, xp, P, ce, gfB, evB, gfA, evA);
    p0 += 8;
  }
  if (p0 < npair){
    run_quad<true,true>(p0, npair, g2l, etl, lane4, g4, xp, P, ce, gfA, evA, gfB, evB);
    if (p0 + 4 < npair)
      run_quad<true,true>(p0+4, npair, g2l, etl, lane4, g4, xp, P, ce, gfB, evB, gfA, evA);
  }

  if (odd){                                 // trailing single step: diag(e)*A
    int v = __builtin_amdgcn_readlane(xp, (n - 1) >> 1);
    int xm = v & 63;                        // n-1 even -> first obs of that pair
    s16x4 af  = *(const s16x4*)&g2[16384 + lane4];   // slot 64 = A frag
    s16x4 evo = *(const s16x4*)&etl[xm*16 + g4];
    const f32x4 Z = {0.f,0.f,0.f,0.f};
    f32x4 C = mfma16(af, P, Z);
    C.x *= b2f((unsigned short)evo.x); C.y *= b2f((unsigned short)evo.y);
    C.z *= b2f((unsigned short)evo.z); C.w *= b2f((unsigned short)evo.w);
    P = pack_bf16x4(C);
  }

  if (g == 0) ceout[j] = ce;
  unsigned short pb[4] = {(unsigned short)P.x, (unsigned short)P.y,
                          (unsigned short)P.z, (unsigned short)P.w};
  #pragma unroll
  for (int e = 0; e < 4; ++e) Qout[(4*g + e)*16 + j] = pb[e];
}

// Combine (verbatim R7): 4 batches/block, one wave per batch; reference
// exponent = readlane(CE[0]); u rescaled once/segment by lane-0 frexp.
__global__ __launch_bounds__(256) void hmm_comb(
    const int* __restrict__ x, const float* __restrict__ ws,
    const unsigned short* __restrict__ Q, const int* __restrict__ CE,
    float* __restrict__ out, int TMAX)
{
  int lane = threadIdx.x & 63;
  int w    = threadIdx.x >> 6;
  int b    = blockIdx.x * 4 + w;
  int k = lane & 15, r = lane >> 4;

  int x0 = x[b*TMAX];
  float u = ws[1024 + k] * ws[x0*16 + k];   // alpha0 = pi * E[:,x0]
  int ce_tot = 0;

  const unsigned short* qb = Q  + (size_t)b * NSEG * 256;
  const int*            cb = CE + b * NSEG * 16;

  // prefetch segment 0
  s16x4 qq = *(const s16x4*)&qb[k*16 + 4*r];       // row k, cols 4r..4r+3
  int4  cv = *(const int4*)&cb[4*r];               // ce[4r..4r+3]

  for (int s = 0; s < NSEG; ++s){
    s16x4 qn; int4 cn;
    if (s + 1 < NSEG){                             // prefetch next segment
      qn = *(const s16x4*)&qb[(s+1)*256 + k*16 + 4*r];
      cn = *(const int4*)&cb[(s+1)*16 + 4*r];
    }
    int c0 = __builtin_amdgcn_readlane(cv.x, 0);   // ce[0] (lane 0: k=0,r=0)
    float m0 = ldexpf(b2f((unsigned short)qq.x), cv.x - c0);
    float m1 = ldexpf(b2f((unsigned short)qq.y), cv.y - c0);
    float m2 = ldexpf(b2f((unsigned short)qq.z), cv.z - c0);
    float m3 = ldexpf(b2f((unsigned short)qq.w), cv.w - c0);

    float u0 = __shfl(u, 4*r + 0);
    float u1 = __shfl(u, 4*r + 1);
    float u2 = __shfl(u, 4*r + 2);
    float u3 = __shfl(u, 4*r + 3);
    float acc = m0*u0 + m1*u1 + m2*u2 + m3*u3;
    acc += __shfl_xor(acc, 16);
    acc += __shfl_xor(acc, 32);                    // full u_new[k] on all r-copies

    int ek; (void)frexpf(acc, &ek);                // exponent of own component
    int k0 = __builtin_amdgcn_readlane(ek, 0);     // rescale by component 0
    u = ldexpf(acc, -k0);
    ce_tot += c0 + k0;

    qq = qn; cv = cn;
  }

  float sm = u;
  sm += __shfl_xor(sm, 1);
  sm += __shfl_xor(sm, 2);
  sm += __shfl_xor(sm, 4);
  sm += __shfl_xor(sm, 8);
  if (lane == 0) out[b] = ldexpf(sm, ce_tot);
}

extern "C" void kernel_launch(void* const* d_in, const int* in_sizes, int n_in,
                              void* d_out, int out_size, void* d_ws, size_t ws_size,
                              hipStream_t stream)
{
  (void)n_in; (void)out_size; (void)ws_size;
  const int*   x  = (const int*)  d_in[0];
  const int*   T  = (const int*)  d_in[1];
  const float* tl = (const float*)d_in[2];
  const float* el = (const float*)d_in[3];
  const float* pl = (const float*)d_in[4];
  int B    = in_sizes[1];
  int TMAX = in_sizes[0] / B;
  int XN   = B * TMAX;

  float* ws = (float*)d_ws;
  unsigned short* g2 = (unsigned short*)((char*)d_ws + 8192);
  unsigned short* Q  = (unsigned short*)((char*)d_ws + 49152);
  int* CE = (int*)((char*)d_ws + 49152 + (size_t)B * NSEG * 512);
  float* out = (float*)d_out;

  hipLaunchKernelGGL(hmm_setup, dim3(65),          dim3(256), 0, stream, tl, el, pl, ws, g2);
  hipLaunchKernelGGL(hmm_seg,   dim3(B*NSEG/8),    dim3(512), 0, stream, x, T, g2, Q, CE, TMAX, XN);
  hipLaunchKernelGGL(hmm_comb,  dim3(B/4),         dim3(256), 0, stream, x, ws, Q, CE, out, TMAX);
}